// Round 3
// baseline (132.056 us; speedup 1.0000x reference)
//
#include <hip/hip_runtime.h>
#include <float.h>

#define K_CODES 1024
#define DIM 64
#define T_LEN 8192
#define N_TOK 131072          // 16 * 8192 tokens
#define LO_SCALE 2048.0f
#define NT_LDS 16             // B tiles staged in LDS (16 * 4 KB = 64 KB)
#define LDS_BYTES (NT_LDS * 4096 + 4096 + 1024)   // tiles + esq(4K) + idx(1K) = 70656

typedef _Float16 half8 __attribute__((ext_vector_type(8)));  // 4 VGPRs: MFMA A/B frag
typedef float    f32x4 __attribute__((ext_vector_type(4)));  // MFMA C/D frag

#define MFMA16(a, b, c) __builtin_amdgcn_mfma_f32_16x16x32_f16((a), (b), (c), 0, 0, 0)

// ---------------- prep: codebook -> tiled f16 hi/lo + 2048*e_sq ----------------
// Tile ct (16 codes) = 4 KB contiguous: hi[q=0..7][code=0..15][j=0..7], lo(x2048) at +1024.
// wesq stores 2048*||e||^2 (exact power-of-2 scale) for the scaled-score argmin.
__global__ void vq_prep(const float* __restrict__ cb,
                        _Float16* __restrict__ w,
                        float* __restrict__ wesq) {
    __shared__ float part[128];
    const int ct   = blockIdx.x;
    const int r    = threadIdx.x;
    const int halF = r >> 7;
    const int rr   = r & 127;
    const int q    = rr >> 4;
    const int code = rr & 15;

    const float* src = cb + (size_t)(ct * 16 + code) * DIM + q * 8;
    float4 v0 = *reinterpret_cast<const float4*>(src);
    float4 v1 = *reinterpret_cast<const float4*>(src + 4);
    float x[8] = {v0.x, v0.y, v0.z, v0.w, v1.x, v1.y, v1.z, v1.w};

    half8 o;
    float psum = 0.0f;
    #pragma unroll
    for (int j = 0; j < 8; ++j) {
        _Float16 h = (_Float16)x[j];
        o[j] = halF ? (_Float16)((x[j] - (float)h) * LO_SCALE) : h;  // (x-h) exact in fp32
        psum = fmaf(x[j], x[j], psum);
    }
    *reinterpret_cast<half8*>(w + (size_t)ct * 2048 + halF * 1024 + q * 128 + code * 8) = o;

    if (halF == 0) part[rr] = psum;
    __syncthreads();
    if (r < 16) {
        float s = 0.0f;
        #pragma unroll
        for (int q2 = 0; q2 < 8; ++q2) s += part[q2 * 16 + r];
        wesq[ct * 16 + r] = s * LO_SCALE;   // pre-scaled: score' = 2048 * score
    }
}

// ---------------- main: 32 tok/wave, 4 waves/SIMD, VGPR<=128 (no AGPR argmin) ----------------
// r1/r2 lesson: neither B-load latency nor MFMA chain depth moved the needle. Invariant both
// times: 2 waves/SIMD with ~190 live regs vs 104 VGPRs -> argmin state in AGPRs (accvgpr
// round-trips inflate VALU) and no cross-wave phase diversity. Fix: halve per-wave state
// (32 tok/wave), 512-thr blocks, launch_bounds(512,4) -> ~116 VGPR demand, 4 waves/SIMD.
// L1 B-traffic doubles, so 16 tiles are staged once in LDS (no loop barriers kept).
// Numerics bit-identical: same MFMA product set + per-chain order per token.
__global__ __launch_bounds__(512, 4)
void vq_main(const float* __restrict__ in,
             const float* __restrict__ cb,
             const _Float16* __restrict__ w,
             const float* __restrict__ wesq,
             float* __restrict__ out) {
    extern __shared__ __align__(16) char smem[];
    _Float16* wlds  = (_Float16*)smem;                      // 64 KB: tiles 0..15
    float*    esq_s = (float*)(smem + NT_LDS * 4096);       // 4 KB (scaled x2048)
    int*      idx_s = (int*)(smem + NT_LDS * 4096 + 4096);  // 1 KB

    const int tid  = threadIdx.x;
    const int wave = tid >> 6;
    const int lane = tid & 63;
    const int lo4  = lane & 15;   // code residue (C col) / token residue (A m)
    const int quad = lane >> 4;   // k-octet selector; token-row group in C

    // ---- one-time cooperative stage: 64 KB of B tiles + esq (single barrier) ----
    {
        const float4* gs = (const float4*)w;
        float4*       ls = (float4*)wlds;
        #pragma unroll
        for (int i = 0; i < NT_LDS * 4096 / 16 / 512; ++i)   // 8 rounds x 512 thr x 16 B
            ls[i * 512 + tid] = gs[i * 512 + tid];
        for (int k = tid; k < K_CODES; k += 512) esq_s[k] = wesq[k];
    }
    __syncthreads();   // only barrier before the epilogue

    const int strip = blockIdx.x * 256 + wave * 32;   // 32 tokens per wave
    const int b  = strip >> 13;
    const int t0 = strip & 8191;

    // ---- A fragments: -2x -> ah (f16), ah_s = ah*2048 (exact), al = (x-ah)*2048 ----
    const float* xin = in + (size_t)b * DIM * T_LEN + t0;
    half8 a_h[2][2], a_hs[2][2], a_l[2][2];   // 48 VGPR
    #pragma unroll
    for (int mt = 0; mt < 2; ++mt) {
        #pragma unroll
        for (int s = 0; s < 2; ++s) {
            half8 hh, hs, ll;
            #pragma unroll
            for (int j = 0; j < 8; ++j) {
                const int d = s * 32 + quad * 8 + j;
                float xv = -2.0f * xin[(size_t)d * T_LEN + mt * 16 + lo4];
                _Float16 h = (_Float16)xv;
                hh[j] = h;
                hs[j] = (_Float16)((float)h * LO_SCALE);            // exact exponent shift
                ll[j] = (_Float16)((xv - (float)h) * LO_SCALE);
            }
            a_h[mt][s] = hh;
            a_hs[mt][s] = hs;
            a_l[mt][s] = ll;
        }
    }

    float best[8];
    int   bidx[8];
    #pragma unroll
    for (int i = 0; i < 8; ++i) { best[i] = FLT_MAX; bidx[i] = 0; }

    // B frags (layout HW-verified r6): tile base + lane*8, frags at +0/+512/+1024/+1536
    const _Float16* wb_g = w    + (size_t)lane * 8;
    const _Float16* wb_l = wlds + (size_t)lane * 8;

    half8 Ah0, Ah1, Al0, Al1, Bh0, Bh1, Bl0, Bl1;
    float Ae, Be;
    auto loadB = [&](int ct, half8& h0, half8& h1, half8& l0, half8& l1, float& es) {
        if (ct < NT_LDS) {      // ds_read_b128 x4, conflict-free
            const _Float16* p = wb_l + (size_t)ct * 2048;
            h0 = *reinterpret_cast<const half8*>(p);          // hi, k 0..31
            h1 = *reinterpret_cast<const half8*>(p + 512);    // hi, k 32..63
            l0 = *reinterpret_cast<const half8*>(p + 1024);   // lo(x2048), k 0..31
            l1 = *reinterpret_cast<const half8*>(p + 1536);   // lo(x2048), k 32..63
        } else {                // global_load_dwordx4 x4 (L1/L2-hot)
            const _Float16* p = wb_g + (size_t)ct * 2048;
            h0 = *reinterpret_cast<const half8*>(p);
            h1 = *reinterpret_cast<const half8*>(p + 512);
            l0 = *reinterpret_cast<const half8*>(p + 1024);
            l1 = *reinterpret_cast<const half8*>(p + 1536);
        }
        es = esq_s[ct * 16 + lo4];
    };
    // Two interleaved accumulator chains (mt=0,1); per-chain MFMA order unchanged
    // -> bit-identical scores vs r0/r2.
    auto step = [&](const half8& h0, const half8& h1, const half8& l0,
                    const half8& l1, float es, int ct) {
        const int code = ct * 16 + lo4;
        f32x4 c0 = {es, es, es, es}, c1 = {es, es, es, es};
        c0 = MFMA16(a_hs[0][0], h0, c0);   // 2048*ah*bh (k 0..31)
        c1 = MFMA16(a_hs[1][0], h0, c1);
        c0 = MFMA16(a_hs[0][1], h1, c0);   // 2048*ah*bh (k 32..63)
        c1 = MFMA16(a_hs[1][1], h1, c1);
        c0 = MFMA16(a_h[0][0], l0, c0);    // ah*(2048*bl)
        c1 = MFMA16(a_h[1][0], l0, c1);
        c0 = MFMA16(a_h[0][1], l1, c0);
        c1 = MFMA16(a_h[1][1], l1, c1);
        c0 = MFMA16(a_l[0][0], h0, c0);    // (2048*al)*bh
        c1 = MFMA16(a_l[1][0], h0, c1);
        c0 = MFMA16(a_l[0][1], h1, c0);
        c1 = MFMA16(a_l[1][1], h1, c1);
        f32x4 cc[2] = {c0, c1};
        #pragma unroll
        for (int mt = 0; mt < 2; ++mt) {
            #pragma unroll
            for (int r = 0; r < 4; ++r) {
                float sc = cc[mt][r];           // scaled score, no fmaf needed
                const int i = mt * 4 + r;
                bool lt = sc < best[i];         // strict <: first occurrence wins
                best[i] = lt ? sc : best[i];
                bidx[i] = lt ? code : bidx[i];
            }
        }
    };

    // ping-pong: tile ct+1's 4 loads in flight during tile ct's 12 MFMAs
    loadB(0, Ah0, Ah1, Al0, Al1, Ae);
    loadB(1, Bh0, Bh1, Bl0, Bl1, Be);
    for (int p = 0; p < 31; ++p) {
        step(Ah0, Ah1, Al0, Al1, Ae, 2 * p);
        loadB(2 * p + 2, Ah0, Ah1, Al0, Al1, Ae);
        step(Bh0, Bh1, Bl0, Bl1, Be, 2 * p + 1);
        loadB(2 * p + 3, Bh0, Bh1, Bl0, Bl1, Be);
    }
    step(Ah0, Ah1, Al0, Al1, Ae, 62);
    step(Bh0, Bh1, Bl0, Bl1, Be, 63);

    // ---- cross-lane merge over the 16 code-residue lanes ----
    #pragma unroll
    for (int i = 0; i < 8; ++i) {
        float s = best[i];
        int  ix = bidx[i];
        #pragma unroll
        for (int off = 1; off < 16; off <<= 1) {
            float s2 = __shfl_xor(s, off, 64);
            int  ix2 = __shfl_xor(ix, off, 64);
            bool take = (s2 < s) || (s2 == s && ix2 < ix);  // tie -> lower index
            s  = take ? s2 : s;
            ix = take ? ix2 : ix;
        }
        if (lo4 == 0) {
            // token_local = mt*16 + quad*4 + r,  mt = i>>2, r = i&3
            idx_s[wave * 32 + (i >> 2) * 16 + quad * 4 + (i & 3)] = ix;
        }
    }
    __syncthreads();

    // ---- epilogue: 512 threads, 256 tokens: each thread does 32 of 64 dims ----
    const int tok_l = tid & 255;
    const int half_ = tid >> 8;
    const int token = blockIdx.x * 256 + tok_l;
    const int tb = token >> 13;
    const int tt = token & 8191;
    const int my_idx = idx_s[tok_l];

    if (half_ == 0)
        out[(size_t)N_TOK * DIM + token] = (float)my_idx;   // index output

    const float* crow = cb + (size_t)my_idx * DIM + half_ * 32;
    float* outv = out + (size_t)tb * DIM * T_LEN + (size_t)(half_ * 32) * T_LEN + tt;
    #pragma unroll
    for (int d0 = 0; d0 < 32; d0 += 4) {
        float4 v = *reinterpret_cast<const float4*>(crow + d0);  // L2-hot gather
        outv[(size_t)(d0 + 0) * T_LEN] = v.x;
        outv[(size_t)(d0 + 1) * T_LEN] = v.y;
        outv[(size_t)(d0 + 2) * T_LEN] = v.z;
        outv[(size_t)(d0 + 3) * T_LEN] = v.w;
    }
}

extern "C" void kernel_launch(void* const* d_in, const int* in_sizes, int n_in,
                              void* d_out, int out_size, void* d_ws, size_t ws_size,
                              hipStream_t stream) {
    const float* in = (const float*)d_in[0];   // (16, 64, 8192) fp32
    const float* cb = (const float*)d_in[1];   // (1024, 64) fp32
    float* out = (float*)d_out;

    _Float16* w   = (_Float16*)d_ws;                       // 64 tiles * 4 KB = 256 KB
    float*   wesq = (float*)((char*)d_ws + 64 * 4096);     // 4 KB

    static bool attr_done = false;
    if (!attr_done) {
        hipFuncSetAttribute(reinterpret_cast<const void*>(vq_main),
                            hipFuncAttributeMaxDynamicSharedMemorySize, LDS_BYTES);
        attr_done = true;
    }

    vq_prep<<<dim3(64), dim3(256), 0, stream>>>(cb, w, wesq);
    vq_main<<<dim3(N_TOK / 256), dim3(512), LDS_BYTES, stream>>>(in, cb, w, wesq, out);
}